// Round 1
// baseline (1512.409 us; speedup 1.0000x reference)
//
#include <hip/hip_runtime.h>
#include <hip/hip_bf16.h>

#define B_ 8
#define C_ 64
#define H_ 256
#define W_ 256
#define K_ 10
#define HW_ (H_*W_)

// ---------------- expert-mixture combine: aw[b] = sum_k attn[b,k] * w[k], transposed to [b][i][tap][o]
__global__ void k_combine_aw(const float* __restrict__ attn,
                             const float* __restrict__ w2,
                             const float* __restrict__ w1,
                             float* __restrict__ aw2T,
                             float* __restrict__ aw1T) {
    const int per = B_*C_*C_*9;
    int gid = blockIdx.x*256 + threadIdx.x;
    if (gid >= 2*per) return;
    const float* w = (gid < per) ? w2 : w1;
    float* outp    = (gid < per) ? aw2T : aw1T;
    int rem = (gid < per) ? gid : gid - per;
    int b  = rem / (C_*C_*9);
    int r2 = rem - b*(C_*C_*9);
    int o  = r2 & 63;
    int it = r2 >> 6;
    int tap = it % 9;
    int i   = it / 9;
    int src = (o*C_ + i)*9 + tap;
    float s = 0.f;
    #pragma unroll
    for (int k = 0; k < K_; ++k)
        s += attn[b*K_ + k] * w[(size_t)k*C_*C_*9 + src];
    outp[rem] = s;
}

// ab = attn @ b ; wT[m][i][o] = w_m[o][i]
__global__ void k_combine_small(const float* __restrict__ attn,
                                const float* __restrict__ b2,
                                const float* __restrict__ b1,
                                const float* __restrict__ w16,
                                const float* __restrict__ w168,
                                const float* __restrict__ w88,
                                float* __restrict__ ab2,
                                float* __restrict__ ab1,
                                float* __restrict__ wT) {
    int gid = blockIdx.x*256 + threadIdx.x;
    if (gid < 512) {
        int b = gid >> 6, o = gid & 63;
        float s = 0.f;
        #pragma unroll
        for (int k = 0; k < K_; ++k) s += attn[b*K_+k]*b2[k*C_+o];
        ab2[gid] = s;
    } else if (gid < 1024) {
        int g = gid - 512;
        int b = g >> 6, o = g & 63;
        float s = 0.f;
        #pragma unroll
        for (int k = 0; k < K_; ++k) s += attn[b*K_+k]*b1[k*C_+o];
        ab1[g] = s;
    } else if (gid < 1024 + 3*4096) {
        int e = gid - 1024;
        int m = e >> 12;
        int r = e & 4095;
        int i = r >> 6, o = r & 63;
        const float* wm = (m==0) ? w16 : (m==1 ? w168 : w88);
        wT[e] = wm[o*C_ + i];
    }
}

// ---------------- stage 1: t = relu((conv3x3(x,aw2)+ab2)*gamma + dyres)  -> bf16
__global__ __launch_bounds__(256) void k_stage1(
    const float* __restrict__ x, const float* __restrict__ par,
    const float* __restrict__ aw2T, const float* __restrict__ ab2,
    const float* __restrict__ gamma, const float* __restrict__ wT,
    __hip_bfloat16* __restrict__ tout)
{
    __shared__ float xs[8][18][19];
    __shared__ float wsh[8][9][64];
    __shared__ float wts[3][8][64];

    const int b   = blockIdx.y;
    const int th0 = (blockIdx.x >> 4) << 4;
    const int tw0 = (blockIdx.x & 15) << 4;
    const int tid = threadIdx.x;
    const int o0  = (tid >> 6) << 4;
    const int lane = tid & 63;
    const int ph = (lane >> 3) << 1;
    const int pw = (lane & 7) << 1;

    float pm[3][4];
    #pragma unroll
    for (int m = 0; m < 3; ++m)
        #pragma unroll
        for (int p = 0; p < 4; ++p) {
            int gh = th0 + ph + (p >> 1);
            int gw = tw0 + pw + (p & 1);
            pm[m][p] = par[((size_t)(b*3 + m))*HW_ + gh*W_ + gw];
        }

    float accc[16][4];
    float accd[16][4];
    #pragma unroll
    for (int j = 0; j < 16; ++j)
        #pragma unroll
        for (int p = 0; p < 4; ++p) { accc[j][p] = 0.f; accd[j][p] = 0.f; }

    const float* xb  = x + (size_t)b*C_*HW_;
    const float* awb = aw2T + (size_t)b*C_*9*C_;

    for (int c0 = 0; c0 < C_; c0 += 8) {
        __syncthreads();
        for (int e = tid; e < 8*18*18; e += 256) {
            int ch = e / 324;
            int rr = e - ch*324;
            int r  = rr / 18;
            int c  = rr - r*18;
            int gh = th0 + r - 1, gw = tw0 + c - 1;
            float v = 0.f;
            if ((unsigned)gh < H_ && (unsigned)gw < W_)
                v = xb[(size_t)(c0+ch)*HW_ + gh*W_ + gw];
            xs[ch][r][c] = v;
        }
        {
            const float* src = awb + c0*9*64;
            float* dst = &wsh[0][0][0];
            for (int e = tid; e < 8*9*64; e += 256) dst[e] = src[e];
        }
        for (int e = tid; e < 3*8*64; e += 256) {
            int m = e >> 9;
            int r = e & 511;
            ((float*)wts)[e] = wT[m*4096 + (c0 + (r >> 6))*64 + (r & 63)];
        }
        __syncthreads();

        for (int ii = 0; ii < 8; ++ii) {
            #pragma unroll
            for (int tap = 0; tap < 9; ++tap) {
                const int kh = tap/3, kw = tap - 3*(tap/3);
                float x00 = xs[ii][ph+kh][pw+kw];
                float x01 = xs[ii][ph+kh][pw+kw+1];
                float x10 = xs[ii][ph+kh+1][pw+kw];
                float x11 = xs[ii][ph+kh+1][pw+kw+1];
                float wv[16];
                #pragma unroll
                for (int q = 0; q < 4; ++q) {
                    float4 f = *(const float4*)&wsh[ii][tap][o0 + 4*q];
                    wv[4*q+0]=f.x; wv[4*q+1]=f.y; wv[4*q+2]=f.z; wv[4*q+3]=f.w;
                }
                #pragma unroll
                for (int j = 0; j < 16; ++j) {
                    accc[j][0] = fmaf(wv[j], x00, accc[j][0]);
                    accc[j][1] = fmaf(wv[j], x01, accc[j][1]);
                    accc[j][2] = fmaf(wv[j], x10, accc[j][2]);
                    accc[j][3] = fmaf(wv[j], x11, accc[j][3]);
                }
                if (tap == 4) {  // fold the three 1x1 convs into the center tap
                    #pragma unroll
                    for (int m = 0; m < 3; ++m) {
                        float t0 = pm[m][0]*x00, t1 = pm[m][1]*x01;
                        float t2 = pm[m][2]*x10, t3 = pm[m][3]*x11;
                        float wm[16];
                        #pragma unroll
                        for (int q = 0; q < 4; ++q) {
                            float4 f = *(const float4*)&wts[m][ii][o0 + 4*q];
                            wm[4*q+0]=f.x; wm[4*q+1]=f.y; wm[4*q+2]=f.z; wm[4*q+3]=f.w;
                        }
                        #pragma unroll
                        for (int j = 0; j < 16; ++j) {
                            accd[j][0] = fmaf(wm[j], t0, accd[j][0]);
                            accd[j][1] = fmaf(wm[j], t1, accd[j][1]);
                            accd[j][2] = fmaf(wm[j], t2, accd[j][2]);
                            accd[j][3] = fmaf(wm[j], t3, accd[j][3]);
                        }
                    }
                }
            }
        }
    }

    __hip_bfloat16* tb = tout + (size_t)b*C_*HW_;
    #pragma unroll
    for (int j = 0; j < 16; ++j) {
        int o = o0 + j;
        float g  = gamma[b*C_ + o];
        float bi = ab2[b*C_ + o];
        #pragma unroll
        for (int p = 0; p < 4; ++p) {
            int gh = th0 + ph + (p >> 1);
            int gw = tw0 + pw + (p & 1);
            float v = (accc[j][p] + bi)*g + accd[j][p];
            v = fmaxf(v, 0.f);
            tb[(size_t)o*HW_ + gh*W_ + gw] = __float2bfloat16(v);
        }
    }
}

// ---------------- stage 2: out = x + (conv3x3(t,aw1)+ab1)*gamma
__global__ __launch_bounds__(256) void k_stage2(
    const __hip_bfloat16* __restrict__ tin, const float* __restrict__ x,
    const float* __restrict__ aw1T, const float* __restrict__ ab1,
    const float* __restrict__ gamma, float* __restrict__ outp)
{
    __shared__ float xs[8][18][19];
    __shared__ float wsh[8][9][64];

    const int b   = blockIdx.y;
    const int th0 = (blockIdx.x >> 4) << 4;
    const int tw0 = (blockIdx.x & 15) << 4;
    const int tid = threadIdx.x;
    const int o0  = (tid >> 6) << 4;
    const int lane = tid & 63;
    const int ph = (lane >> 3) << 1;
    const int pw = (lane & 7) << 1;

    float accc[16][4];
    #pragma unroll
    for (int j = 0; j < 16; ++j)
        #pragma unroll
        for (int p = 0; p < 4; ++p) accc[j][p] = 0.f;

    const __hip_bfloat16* tb = tin + (size_t)b*C_*HW_;
    const float* awb = aw1T + (size_t)b*C_*9*C_;

    for (int c0 = 0; c0 < C_; c0 += 8) {
        __syncthreads();
        for (int e = tid; e < 8*18*18; e += 256) {
            int ch = e / 324;
            int rr = e - ch*324;
            int r  = rr / 18;
            int c  = rr - r*18;
            int gh = th0 + r - 1, gw = tw0 + c - 1;
            float v = 0.f;
            if ((unsigned)gh < H_ && (unsigned)gw < W_)
                v = __bfloat162float(tb[(size_t)(c0+ch)*HW_ + gh*W_ + gw]);
            xs[ch][r][c] = v;
        }
        {
            const float* src = awb + c0*9*64;
            float* dst = &wsh[0][0][0];
            for (int e = tid; e < 8*9*64; e += 256) dst[e] = src[e];
        }
        __syncthreads();

        for (int ii = 0; ii < 8; ++ii) {
            #pragma unroll
            for (int tap = 0; tap < 9; ++tap) {
                const int kh = tap/3, kw = tap - 3*(tap/3);
                float x00 = xs[ii][ph+kh][pw+kw];
                float x01 = xs[ii][ph+kh][pw+kw+1];
                float x10 = xs[ii][ph+kh+1][pw+kw];
                float x11 = xs[ii][ph+kh+1][pw+kw+1];
                float wv[16];
                #pragma unroll
                for (int q = 0; q < 4; ++q) {
                    float4 f = *(const float4*)&wsh[ii][tap][o0 + 4*q];
                    wv[4*q+0]=f.x; wv[4*q+1]=f.y; wv[4*q+2]=f.z; wv[4*q+3]=f.w;
                }
                #pragma unroll
                for (int j = 0; j < 16; ++j) {
                    accc[j][0] = fmaf(wv[j], x00, accc[j][0]);
                    accc[j][1] = fmaf(wv[j], x01, accc[j][1]);
                    accc[j][2] = fmaf(wv[j], x10, accc[j][2]);
                    accc[j][3] = fmaf(wv[j], x11, accc[j][3]);
                }
            }
        }
    }

    const float* xb = x + (size_t)b*C_*HW_;
    float* ob = outp + (size_t)b*C_*HW_;
    #pragma unroll
    for (int j = 0; j < 16; ++j) {
        int o = o0 + j;
        float g  = gamma[b*C_ + o];
        float bi = ab1[b*C_ + o];
        #pragma unroll
        for (int p = 0; p < 4; ++p) {
            int gh = th0 + ph + (p >> 1);
            int gw = tw0 + pw + (p & 1);
            size_t idx = (size_t)o*HW_ + gh*W_ + gw;
            ob[idx] = xb[idx] + (accc[j][p] + bi)*g;
        }
    }
}

extern "C" void kernel_launch(void* const* d_in, const int* in_sizes, int n_in,
                              void* d_out, int out_size, void* d_ws, size_t ws_size,
                              hipStream_t stream) {
    const float* x     = (const float*)d_in[0];
    const float* attn  = (const float*)d_in[1];
    const float* gamma = (const float*)d_in[2];
    const float* par   = (const float*)d_in[3];
    const float* w1    = (const float*)d_in[4];
    const float* b1    = (const float*)d_in[5];
    const float* w2    = (const float*)d_in[6];
    const float* b2    = (const float*)d_in[7];
    const float* w16   = (const float*)d_in[8];
    const float* w168  = (const float*)d_in[9];
    const float* w88   = (const float*)d_in[10];
    float* out = (float*)d_out;

    float* wsf  = (float*)d_ws;
    float* aw2T = wsf;                    // 2359296 floats
    float* aw1T = wsf + 2359296;          // 2359296 floats
    float* ab2  = wsf + 4718592;          // 512
    float* ab1  = ab2 + 512;              // 512
    float* wT   = ab1 + 512;              // 12288
    __hip_bfloat16* tbuf = (__hip_bfloat16*)(wT + 3*4096);  // 33.5M bf16

    k_combine_aw<<<dim3(2304), dim3(256), 0, stream>>>(attn, w2, w1, aw2T, aw1T);
    k_combine_small<<<dim3(52), dim3(256), 0, stream>>>(attn, b2, b1, w16, w168, w88, ab2, ab1, wT);

    dim3 grid(256, 8);
    k_stage1<<<grid, dim3(256), 0, stream>>>(x, par, aw2T, ab2, gamma, wT, tbuf);
    k_stage2<<<grid, dim3(256), 0, stream>>>(tbuf, x, aw1T, ab1, gamma, out);
}

// Round 2
// 263.262 us; speedup vs baseline: 5.7449x; 5.7449x over previous
//
#include <hip/hip_runtime.h>
#include <hip/hip_bf16.h>

typedef __attribute__((ext_vector_type(8))) short short8;
typedef __attribute__((ext_vector_type(4))) float f32x4;

#define B_ 8
#define C_ 64
#define H_ 256
#define W_ 256
#define HW_ 65536
#define K_ 10
#define NS1 24
#define NS2 18

static __device__ __forceinline__ unsigned short f2bf(float f) {
    __hip_bfloat16 hb = __float2bfloat16(f);
    return *(unsigned short*)&hb;
}
static __device__ __forceinline__ float bf2f(unsigned short u) {
    unsigned v = ((unsigned)u) << 16;
    float f;
    __builtin_memcpy(&f, &v, 4);
    return f;
}

// ---------------------------------------------------------------------------
// Build fragment-ordered, gamma-folded, expert-mixed weights + biases.
// W4_1: [b][24 steps][4 ofrag][64 lane][8] bf16   (steps 0..17: conv taps, 18..23: 1x1 experts)
// W4_2: [b][18 steps][4][64][8] bf16
// ---------------------------------------------------------------------------
__global__ void k_combine(const float* __restrict__ attn, const float* __restrict__ gamma,
                          const float* __restrict__ w1, const float* __restrict__ b1,
                          const float* __restrict__ w2, const float* __restrict__ b2,
                          const float* __restrict__ w16, const float* __restrict__ w168,
                          const float* __restrict__ w88,
                          unsigned short* __restrict__ W4_1, unsigned short* __restrict__ W4_2,
                          float* __restrict__ bias1, float* __restrict__ bias2) {
    const int N1 = B_ * NS1 * 2048;   // 393216
    const int N2 = B_ * NS2 * 2048;   // 294912
    int gid = blockIdx.x * 256 + threadIdx.x;
    if (gid < N1) {
        int b = gid / (NS1 * 2048);
        int r = gid - b * (NS1 * 2048);
        int s = r >> 11;
        int r2 = r & 2047;
        int of = r2 >> 9, l = (r2 >> 3) & 63, j = r2 & 7;
        int o = of * 16 + (l & 15);
        int g = l >> 4;
        float val;
        if (s < 18) {
            int t = s >> 1, h = s & 1;
            int c = h * 32 + g * 8 + j;
            float acc = 0.f;
            #pragma unroll
            for (int k = 0; k < K_; ++k)
                acc += attn[b * K_ + k] * w2[((size_t)(k * 64 + o) * 64 + c) * 9 + t];
            val = acc * gamma[b * 64 + o];
        } else {
            int e = s - 18;
            int m = e >> 1, h = e & 1;
            int c = h * 32 + g * 8 + j;
            const float* wm = (m == 0) ? w16 : (m == 1 ? w168 : w88);
            val = wm[o * 64 + c];
        }
        W4_1[gid] = f2bf(val);
    } else if (gid < N1 + N2) {
        int gid2 = gid - N1;
        int b = gid2 / (NS2 * 2048);
        int r = gid2 - b * (NS2 * 2048);
        int s = r >> 11;
        int r2 = r & 2047;
        int of = r2 >> 9, l = (r2 >> 3) & 63, j = r2 & 7;
        int o = of * 16 + (l & 15);
        int g = l >> 4;
        int t = s >> 1, h = s & 1;
        int c = h * 32 + g * 8 + j;
        float acc = 0.f;
        #pragma unroll
        for (int k = 0; k < K_; ++k)
            acc += attn[b * K_ + k] * w1[((size_t)(k * 64 + o) * 64 + c) * 9 + t];
        W4_2[gid2] = f2bf(acc * gamma[b * 64 + o]);
    } else if (gid < N1 + N2 + 1024) {
        int id2 = gid - N1 - N2;
        int b = id2 >> 7;
        int rest = id2 & 127;
        int o = rest >> 1;
        int which = rest & 1;
        const float* bb = which ? b1 : b2;
        float acc = 0.f;
        #pragma unroll
        for (int k = 0; k < K_; ++k) acc += attn[b * K_ + k] * bb[k * 64 + o];
        float v = acc * gamma[b * 64 + o];
        if (which) bias2[b * 64 + o] = v; else bias1[b * 64 + o] = v;
    }
}

// ---------------------------------------------------------------------------
// x [b][64][HW] f32  ->  X1 [b][HW][64] bf16   (coalesced transpose)
// ---------------------------------------------------------------------------
__global__ __launch_bounds__(256) void k_prep(const float* __restrict__ x,
                                              unsigned short* __restrict__ X1) {
    __shared__ float ls[64][65];
    const int b = blockIdx.y;
    const int px0 = blockIdx.x * 64;
    const int t = threadIdx.x;
    for (int e = t; e < 4096; e += 256) {
        int ch = e >> 6, px = e & 63;
        ls[ch][px] = x[((size_t)b * 64 + ch) * HW_ + px0 + px];
    }
    __syncthreads();
    for (int e = t; e < 4096; e += 256) {
        int ch = e & 63, px = e >> 6;
        X1[((size_t)b * HW_ + px0 + px) * 64 + ch] = f2bf(ls[ch][px]);
    }
}

// ---------------------------------------------------------------------------
// Implicit-GEMM conv3x3 via MFMA.
// Block: 4 waves, tile = 4 img-rows x 32 w x 64 o.  A from LDS slab (swizzled),
// B frags direct from global (fragment-ordered, L2-resident).
// ---------------------------------------------------------------------------
template<int STAGE>
__global__ __launch_bounds__(256) void k_conv(
    const unsigned short* __restrict__ Xin,   // [b][px][64] bf16
    const float* __restrict__ x_res,          // stage2 residual [b][o][px]
    const float* __restrict__ par,            // stage1 [b][3][HW]
    const unsigned short* __restrict__ W4,    // [b][NS][4][64][8] bf16
    const float* __restrict__ bias,           // [b][64]
    unsigned short* __restrict__ Tout,        // stage1 out [b][px][64] bf16
    float* __restrict__ Fout)                 // stage2 out [b][64][HW] f32
{
    __shared__ short xs[6 * 40 * 64];   // 30720 B, rows of 128B, XOR-swizzled 16B slots

    const int tid = threadIdx.x;
    const int l = tid & 63;
    const int wv = tid >> 6;            // img-row within tile
    const int b = blockIdx.y;
    const int rblk = blockIdx.x >> 3;   // 0..63
    const int cblk = blockIdx.x & 7;    // 0..7
    const int gh0 = rblk * 4, w0 = cblk * 32;
    const int ln15 = l & 15, g = l >> 4;

    const unsigned short* Xb = Xin + (size_t)b * HW_ * 64;
    const unsigned short* Wb = W4 + (size_t)b * ((STAGE == 1 ? NS1 : NS2) * 2048);

    f32x4 acc[2][4];
    #pragma unroll
    for (int mf = 0; mf < 2; ++mf)
        #pragma unroll
        for (int of = 0; of < 4; ++of)
            acc[mf][of] = (f32x4){0.f, 0.f, 0.f, 0.f};

    // ---- stage main slab: [6 rows][40 w][64 ch], zero-padded at image edges
    #pragma unroll 1
    for (int it = 0; it < 8; ++it) {
        int tau = tid + it * 256;
        if (tau < 1920) {
            int slot = tau & 7;
            int rest = tau >> 3;
            int w = rest % 40;
            int rr = rest / 40;
            int gh = gh0 + rr - 1, gw = w0 + w - 1;
            short8 v = {0, 0, 0, 0, 0, 0, 0, 0};
            if ((unsigned)gh < H_ && (unsigned)gw < W_) {
                int cb = slot ^ (w & 7);
                v = *(const short8*)(Xb + ((size_t)(gh * W_ + gw)) * 64 + cb * 8);
            }
            *(short8*)((char*)xs + (rr * 40 + w) * 128 + slot * 16) = v;
        }
    }
    __syncthreads();

    int step = 0;
    // ---- 9 taps x 2 K-halves
    #pragma unroll
    for (int dh = 0; dh < 3; ++dh) {
        #pragma unroll
        for (int dw = 0; dw < 3; ++dw) {
            #pragma unroll
            for (int h = 0; h < 2; ++h) {
                const unsigned short* wp = Wb + step * 2048 + l * 8;
                short8 bf0 = *(const short8*)(wp);
                short8 bf1 = *(const short8*)(wp + 512);
                short8 bf2 = *(const short8*)(wp + 1024);
                short8 bf3 = *(const short8*)(wp + 1536);
                #pragma unroll
                for (int mf = 0; mf < 2; ++mf) {
                    int wr = 16 * mf + ln15 + dw;
                    int row = (wv + dh) * 40 + wr;
                    int slot = ((h << 2) | g) ^ (wr & 7);
                    short8 af = *(const short8*)((const char*)xs + row * 128 + slot * 16);
                    acc[mf][0] = __builtin_amdgcn_mfma_f32_16x16x32_bf16(af, bf0, acc[mf][0], 0, 0, 0);
                    acc[mf][1] = __builtin_amdgcn_mfma_f32_16x16x32_bf16(af, bf1, acc[mf][1], 0, 0, 0);
                    acc[mf][2] = __builtin_amdgcn_mfma_f32_16x16x32_bf16(af, bf2, acc[mf][2], 0, 0, 0);
                    acc[mf][3] = __builtin_amdgcn_mfma_f32_16x16x32_bf16(af, bf3, acc[mf][3], 0, 0, 0);
                }
                ++step;
            }
        }
    }

    if constexpr (STAGE == 1) {
        // ---- three par_m-scaled 1x1 groups, center tap only
        #pragma unroll 1
        for (int m = 0; m < 3; ++m) {
            __syncthreads();
            #pragma unroll 1
            for (int it = 0; it < 4; ++it) {
                int tau = tid + it * 256;
                int slot = tau & 7;
                int rest = tau >> 3;       // 0..127
                int w = 1 + (rest & 31);
                int rr = 1 + (rest >> 5);  // 1..4
                int cb = slot ^ (w & 7);
                int px = (gh0 + rr - 1) * W_ + (w0 + w - 1);
                short8 v = *(const short8*)(Xb + (size_t)px * 64 + cb * 8);
                float pv = par[((size_t)b * 3 + m) * HW_ + px];
                short8 o8;
                #pragma unroll
                for (int q = 0; q < 8; ++q)
                    o8[q] = (short)f2bf(bf2f((unsigned short)v[q]) * pv);
                *(short8*)((char*)xs + (rr * 40 + w) * 128 + slot * 16) = o8;
            }
            __syncthreads();
            #pragma unroll
            for (int h = 0; h < 2; ++h) {
                const unsigned short* wp = Wb + step * 2048 + l * 8;
                short8 bf0 = *(const short8*)(wp);
                short8 bf1 = *(const short8*)(wp + 512);
                short8 bf2 = *(const short8*)(wp + 1024);
                short8 bf3 = *(const short8*)(wp + 1536);
                #pragma unroll
                for (int mf = 0; mf < 2; ++mf) {
                    int wr = 16 * mf + ln15 + 1;
                    int row = (wv + 1) * 40 + wr;
                    int slot = ((h << 2) | g) ^ (wr & 7);
                    short8 af = *(const short8*)((const char*)xs + row * 128 + slot * 16);
                    acc[mf][0] = __builtin_amdgcn_mfma_f32_16x16x32_bf16(af, bf0, acc[mf][0], 0, 0, 0);
                    acc[mf][1] = __builtin_amdgcn_mfma_f32_16x16x32_bf16(af, bf1, acc[mf][1], 0, 0, 0);
                    acc[mf][2] = __builtin_amdgcn_mfma_f32_16x16x32_bf16(af, bf2, acc[mf][2], 0, 0, 0);
                    acc[mf][3] = __builtin_amdgcn_mfma_f32_16x16x32_bf16(af, bf3, acc[mf][3], 0, 0, 0);
                }
                ++step;
            }
        }
    }

    // ---- epilogue
    const int gh = gh0 + wv;
    if constexpr (STAGE == 1) {
        #pragma unroll
        for (int of = 0; of < 4; ++of) {
            int o = of * 16 + ln15;
            float bi = bias[b * 64 + o];
            #pragma unroll
            for (int mf = 0; mf < 2; ++mf) {
                #pragma unroll
                for (int q = 0; q < 4; ++q) {
                    int gw = w0 + 16 * mf + g * 4 + q;
                    float v = acc[mf][of][q] + bi;
                    v = fmaxf(v, 0.f);
                    Tout[((size_t)b * HW_ + gh * W_ + gw) * 64 + o] = f2bf(v);
                }
            }
        }
    } else {
        #pragma unroll
        for (int of = 0; of < 4; ++of) {
            int o = of * 16 + ln15;
            float bi = bias[b * 64 + o];
            #pragma unroll
            for (int mf = 0; mf < 2; ++mf) {
                int gw = w0 + 16 * mf + g * 4;
                size_t idx = ((size_t)b * 64 + o) * HW_ + gh * W_ + gw;
                f32x4 xv = *(const f32x4*)(x_res + idx);
                f32x4 ov;
                #pragma unroll
                for (int q = 0; q < 4; ++q) ov[q] = xv[q] + acc[mf][of][q] + bi;
                *(f32x4*)(Fout + idx) = ov;
            }
        }
    }
}

extern "C" void kernel_launch(void* const* d_in, const int* in_sizes, int n_in,
                              void* d_out, int out_size, void* d_ws, size_t ws_size,
                              hipStream_t stream) {
    const float* x     = (const float*)d_in[0];
    const float* attn  = (const float*)d_in[1];
    const float* gamma = (const float*)d_in[2];
    const float* par   = (const float*)d_in[3];
    const float* w1    = (const float*)d_in[4];
    const float* b1    = (const float*)d_in[5];
    const float* w2    = (const float*)d_in[6];
    const float* b2    = (const float*)d_in[7];
    const float* w16   = (const float*)d_in[8];
    const float* w168  = (const float*)d_in[9];
    const float* w88   = (const float*)d_in[10];
    float* out = (float*)d_out;

    char* w = (char*)d_ws;
    unsigned short* W4_1 = (unsigned short*)w;                       // 786432 B
    unsigned short* W4_2 = (unsigned short*)(w + 786432);            // 589824 B
    float* bias1 = (float*)(w + 786432 + 589824);                    // 2048 B
    float* bias2 = (float*)(w + 786432 + 589824 + 2048);             // 2048 B
    unsigned short* X1 = (unsigned short*)(w + 1380352);             // 67108864 B
    unsigned short* T  = (unsigned short*)(w + 1380352 + 67108864);  // 67108864 B

    k_combine<<<dim3(2692), dim3(256), 0, stream>>>(attn, gamma, w1, b1, w2, b2,
                                                    w16, w168, w88, W4_1, W4_2, bias1, bias2);
    k_prep<<<dim3(1024, 8), dim3(256), 0, stream>>>(x, X1);

    dim3 grid(512, 8);
    k_conv<1><<<grid, dim3(256), 0, stream>>>(X1, nullptr, par, W4_1, bias1, T, nullptr);
    k_conv<2><<<grid, dim3(256), 0, stream>>>(T, x, nullptr, W4_2, bias2, nullptr, out);
}